// Round 4
// baseline (268.665 us; speedup 1.0000x reference)
//
#include <hip/hip_runtime.h>

// MPS encoder, segmented-chain, register-resident product, prefetched A-frags.
// SEGLEN=32, NSEG=4, BT=32, 1024-thr blocks, grid 64x4 = 256 = 1 block/CU.
// Per site: build M_n (fp8 MFMA, A-frags prefetched during previous product
// phase), fold into per-wave register product P (packed fp8) via ds_bpermute.
// Scaling: core8 = fp8(16*core); P stored = 16*true; combine /16 per seg.

#define NSITES 128
#define FEATD  64
#define BOND   32
#define OUTD   256
#define BT     32
#define SEGLEN 32
#define NSEG   (NSITES / SEGLEN)   // 4
#define NBT    (2048 / BT)         // 64

#define RSTRIDE 48        // LDS row stride (32 B payload + 16 pad)
#define BSTRIDE 1552      // 32*48 + 16 (batch stride)

typedef __attribute__((ext_vector_type(4))) float float4v;

__device__ __forceinline__ unsigned pk4_fp8(float a, float b, float c, float d) {
    int v = __builtin_amdgcn_cvt_pk_fp8_f32(a, b, 0, false);
    v = __builtin_amdgcn_cvt_pk_fp8_f32(c, d, v, true);
    return (unsigned)v;
}

// cores [n][d][f][r] fp32 -> core8 [n][c=d*32+r][f] fp8 (x16), LDS transpose.
__global__ __launch_bounds__(256)
void prep_cores8(const float* __restrict__ cores, unsigned char* __restrict__ core8) {
    __shared__ float tile[FEATD][BOND + 4];
    const int nd = blockIdx.x;            // n*32 + d
    const int t  = threadIdx.x;
    const float* src = cores + (size_t)nd * (FEATD * BOND);
    {
        int base = t * 8;
        int f = base >> 5, r0 = base & 31;
        float4 v0 = *(const float4*)(src + base);
        float4 v1 = *(const float4*)(src + base + 4);
        tile[f][r0 + 0] = v0.x; tile[f][r0 + 1] = v0.y;
        tile[f][r0 + 2] = v0.z; tile[f][r0 + 3] = v0.w;
        tile[f][r0 + 4] = v1.x; tile[f][r0 + 5] = v1.y;
        tile[f][r0 + 6] = v1.z; tile[f][r0 + 7] = v1.w;
    }
    __syncthreads();
    const int r = t >> 3, f0 = (t & 7) * 8;
    const float s = 16.0f;
    unsigned lo = pk4_fp8(tile[f0 + 0][r] * s, tile[f0 + 1][r] * s,
                          tile[f0 + 2][r] * s, tile[f0 + 3][r] * s);
    unsigned hi = pk4_fp8(tile[f0 + 4][r] * s, tile[f0 + 5][r] * s,
                          tile[f0 + 6][r] * s, tile[f0 + 7][r] * s);
    uint2 w; w.x = lo; w.y = hi;
    *(uint2*)(core8 + ((size_t)nd * BOND + r) * FEATD + f0) = w;
}

__global__ __launch_bounds__(1024, 4)   // <=128 VGPR, 1 block/CU target
void mps_seg(const float* __restrict__ x, const unsigned char* __restrict__ core8,
             unsigned char* __restrict__ Pout) {
    __shared__ __align__(16) unsigned char MS[BT * BSTRIDE];   // 49664 B
    __shared__ __align__(16) unsigned char XS[BT * 72];        //  2304 B

    const int t    = threadIdx.x;
    const int wave = t >> 6;          // 0..15
    const int lane = t & 63;
    const int cl   = lane & 15;
    const int q    = lane >> 4;
    const int cb   = wave & 7;        // c-block (8 tiles each)
    const int bh   = wave >> 3;       // batch half for build
    const int b0   = blockIdx.x * BT;
    const int seg  = blockIdx.y;

    // Register-resident product, packed fp8 (P = 16*I init; fp8(16)=0x58).
    int pw[2][2][2];
#pragma unroll
    for (int bi = 0; bi < 2; ++bi)
#pragma unroll
        for (int I = 0; I < 2; ++I)
#pragma unroll
            for (int J = 0; J < 2; ++J) {
                int v = 0;
                int g = cl - 4 * q;
                if (I == J && g >= 0 && g < 4) v = 0x58 << (g * 8);
                pw[bi][I][J] = v;
            }

    const int hi32  = (lane & 32) ? 1 : 0;
    const int addr0 = (cl + ((lane & 16) << 1)) * 4;
    const int addr1 = addr0 + 64;

    // x staging indices: 32 batches x 32 float-pairs
    const int xb = t >> 5, xf = (t & 31) * 2;
    // A-fragment lane offsets (site-invariant)
    const unsigned afoff = (unsigned)((cb * 8 * 16 + cl) * FEATD + q * 8);

    // preheader: stage XS(0), load af(0)
    {
        float2 x0 = *(const float2*)(x + ((size_t)(b0 + xb) * NSITES + seg * SEGLEN) * FEATD + xf);
        int v = __builtin_amdgcn_cvt_pk_fp8_f32(x0.x, x0.y, 0, false);
        *(unsigned short*)&XS[xb * 72 + xf] = (unsigned short)(v & 0xffff);
    }
    long af[16];
    {
        const unsigned char* p0 = core8 + (size_t)(seg * SEGLEN) * (1024 * FEATD) + afoff;
#pragma unroll
        for (int i = 0; i < 8; ++i) {
            af[i * 2 + 0] = *(const long*)(p0 + i * (16 * FEATD));
            af[i * 2 + 1] = *(const long*)(p0 + i * (16 * FEATD) + 32);
        }
    }

    for (int k = 0; k < SEGLEN; ++k) {
        const int n = seg * SEGLEN + k;
        __syncthreads();   // barrier A: XS(k) visible, MS(k-1) reads done, af(k) arrived

        // build: m^T[c,b], c-tiles T = cb*8+i, batches bh*16..+15
        long bx0 = *(const long*)&XS[(bh * 16 + cl) * 72 + q * 8];
        long bx1 = *(const long*)&XS[(bh * 16 + cl) * 72 + 32 + q * 8];
        float4v acc[8];
#pragma unroll
        for (int i = 0; i < 8; ++i) {
            float4v z = {0.f, 0.f, 0.f, 0.f};
            z = __builtin_amdgcn_mfma_f32_16x16x32_fp8_fp8(af[i * 2 + 0], bx0, z, 0, 0, 0);
            acc[i] = __builtin_amdgcn_mfma_f32_16x16x32_fp8_fp8(af[i * 2 + 1], bx1, z, 0, 0, 0);
        }
        // MS[b=bh*16+cl][r=16p+4q+g][d-pack at byte cb*4]; tile T=cb*8+2u+p -> acc[2u+p]
#pragma unroll
        for (int p = 0; p < 2; ++p)
#pragma unroll
            for (int g = 0; g < 4; ++g) {
                unsigned w = pk4_fp8(acc[p][g], acc[p + 2][g], acc[p + 4][g], acc[p + 6][g]);
                *(unsigned*)&MS[(bh * 16 + cl) * BSTRIDE + (16 * p + 4 * q + g) * RSTRIDE + cb * 4] = w;
            }

        __syncthreads();   // barrier B: MS(k) visible

        // prefetch af(k+1) + x(k+1) NOW -> latency hidden under product phase
        float2 xn;
        if (k + 1 < SEGLEN) {
            xn = *(const float2*)(x + ((size_t)(b0 + xb) * NSITES + n + 1) * FEATD + xf);
            const unsigned char* p1 = core8 + (size_t)(n + 1) * (1024 * FEATD) + afoff;
#pragma unroll
            for (int i = 0; i < 8; ++i) {
                af[i * 2 + 0] = *(const long*)(p1 + i * (16 * FEATD));
                af[i * 2 + 1] = *(const long*)(p1 + i * (16 * FEATD) + 32);
            }
        }

        // product: P <- M * P per batch (wave owns batches wave*2, wave*2+1)
#pragma unroll
        for (int bi = 0; bi < 2; ++bi) {
            const int bb = wave * 2 + bi;
            long pa0 = *(const long*)&MS[bb * BSTRIDE + (0 * 16 + cl) * RSTRIDE + q * 8];
            long pa1 = *(const long*)&MS[bb * BSTRIDE + (1 * 16 + cl) * RSTRIDE + q * 8];
            long pbv[2];
#pragma unroll
            for (int h = 0; h < 2; ++h) {
                int l0a = __builtin_amdgcn_ds_bpermute(addr0, pw[bi][0][h]);
                int l0b = __builtin_amdgcn_ds_bpermute(addr0, pw[bi][1][h]);
                int l1a = __builtin_amdgcn_ds_bpermute(addr1, pw[bi][0][h]);
                int l1b = __builtin_amdgcn_ds_bpermute(addr1, pw[bi][1][h]);
                int d0 = hi32 ? l0b : l0a;
                int d1 = hi32 ? l1b : l1a;
                pbv[h] = ((long)(unsigned)d0) | (((long)d1) << 32);
            }
            float4v pc[2][2];
#pragma unroll
            for (int I = 0; I < 2; ++I)
#pragma unroll
                for (int J = 0; J < 2; ++J) {
                    float4v z = {0.f, 0.f, 0.f, 0.f};
                    pc[I][J] = __builtin_amdgcn_mfma_f32_16x16x32_fp8_fp8(
                        I ? pa1 : pa0, pbv[J], z, 0, 0, 0);
                }
#pragma unroll
            for (int I = 0; I < 2; ++I)
#pragma unroll
                for (int J = 0; J < 2; ++J)
                    pw[bi][I][J] = (int)pk4_fp8(pc[I][J][0] * 0.0625f, pc[I][J][1] * 0.0625f,
                                                pc[I][J][2] * 0.0625f, pc[I][J][3] * 0.0625f);
        }

        // stage XS(k+1): all XS(k) reads happened before barrier B
        if (k + 1 < SEGLEN) {
            int v = __builtin_amdgcn_cvt_pk_fp8_f32(xn.x, xn.y, 0, false);
            *(unsigned short*)&XS[xb * 72 + xf] = (unsigned short)(v & 0xffff);
        }
    }

    // dump: stage pw into MS (flat [b][1024]), then coalesced copy to Pout
    __syncthreads();   // last product's MS reads done
#pragma unroll
    for (int bi = 0; bi < 2; ++bi) {
        const int bb = wave * 2 + bi;
#pragma unroll
        for (int I = 0; I < 2; ++I)
#pragma unroll
            for (int J = 0; J < 2; ++J)
                *(unsigned*)&MS[bb * 1024 + (J * 16 + cl) * 32 + I * 16 + q * 4] =
                    (unsigned)pw[bi][I][J];
    }
    __syncthreads();
    {
        int b = t >> 5, chunk = t & 31;
        const uint4* p = (const uint4*)&MS[b * 1024 + chunk * 32];
        uint4 v0 = p[0];
        uint4 v1 = p[1];
        uint4* g = (uint4*)(Pout + (((size_t)seg * 2048 + b0 + b) * 1024 + chunk * 32));
        g[0] = v0;
        g[1] = v1;
    }
}

// one wave per batch: res'[beta] = sum_alpha res[alpha] * fp8(P[alpha][beta]) / 16
__global__ __launch_bounds__(512)
void combine(const unsigned char* __restrict__ Pout, const float* __restrict__ startv,
             const float* __restrict__ endv, const float* __restrict__ fc_w,
             const float* __restrict__ fc_b, float* __restrict__ out) {
    const int t    = threadIdx.x;
    const int wave = t >> 6;
    const int lane = t & 63;
    const int r    = lane >> 1;   // beta, duplicated on lane pairs
    const int dh   = lane & 1;    // alpha half
    const int b    = blockIdx.x * 8 + wave;

    float res = startv[r];
    const unsigned char* base = Pout + (size_t)b * 1024 + dh * 512 + r;

    unsigned char by[16];
#pragma unroll
    for (int di = 0; di < 16; ++di) by[di] = base[di * 32];

    for (int s = 0; s < NSEG; ++s) {
        unsigned char by2[16];
        if (s + 1 < NSEG) {
            const unsigned char* nb = base + (size_t)(s + 1) * 2048 * 1024;
#pragma unroll
            for (int di = 0; di < 16; ++di) by2[di] = nb[di * 32];
        }
        float acc = 0.f;
#pragma unroll
        for (int di = 0; di < 16; ++di) {
            float rv = __shfl(res, dh * 32 + di * 2, 64);   // res[alpha], alpha=dh*16+di
            acc += rv * __builtin_amdgcn_cvt_f32_fp8((int)by[di], 0);
        }
        float tot = acc + __shfl_xor(acc, 1, 64);
        res = tot * 0.0625f;
        if (s + 1 < NSEG) {
#pragma unroll
            for (int di = 0; di < 16; ++di) by[di] = by2[di];
        }
    }

    float v = dh ? 0.f : res * endv[r];
#pragma unroll
    for (int off = 1; off < 64; off <<= 1) v += __shfl_xor(v, off, 64);

    const int j = lane * 4;
    float4 w4  = *(const float4*)(fc_w + j);
    float4 bb4 = *(const float4*)(fc_b + j);
    float4 o;
    o.x = v * w4.x + bb4.x;
    o.y = v * w4.y + bb4.y;
    o.z = v * w4.z + bb4.z;
    o.w = v * w4.w + bb4.w;
    *(float4*)(out + (size_t)b * OUTD + j) = o;
}

extern "C" void kernel_launch(void* const* d_in, const int* in_sizes, int n_in,
                              void* d_out, int out_size, void* d_ws, size_t ws_size,
                              hipStream_t stream) {
    const float* x      = (const float*)d_in[0];
    const float* cores  = (const float*)d_in[1];
    const float* startv = (const float*)d_in[2];
    const float* endv   = (const float*)d_in[3];
    const float* fc_w   = (const float*)d_in[4];
    const float* fc_b   = (const float*)d_in[5];
    float* out = (float*)d_out;

    unsigned char* core8 = (unsigned char*)d_ws;                       // 8.4 MB
    unsigned char* Pout  = core8 + (size_t)NSITES * 1024 * FEATD;      // 8.4 MB

    prep_cores8<<<NSITES * BOND, 256, 0, stream>>>(cores, core8);
    mps_seg<<<dim3(NBT, NSEG), 1024, 0, stream>>>(x, core8, Pout);
    combine<<<2048 / 8, 512, 0, stream>>>(Pout, startv, endv, fc_w, fc_b, out);
}

// Round 5
// 252.982 us; speedup vs baseline: 1.0620x; 1.0620x over previous
//
#include <hip/hip_runtime.h>

// MPS encoder, segmented chain. BT=16 batches/block, SEGLEN=32, NSEG=4,
// 512-thr blocks, grid 128x4=512 = 2 blocks/CU (phase overlap across blocks).
// Build: M_n via 16x16x32 fp8 MFMA (A-frags prefetched to VGPRs during the
// previous product phase), M^T packed to LDS MS[r][b][d].
// Product: Q <- M^T * Q per batch via ONE 32x32x16 fp8 MFMA pair; Q = P^T
// lives in registers as 4 packed-fp8 dwords/lane/batch; B-operand built with
// 4 ds_bpermute (lane^32 swap) + selects.
// Scaling: core8 = fp8(16*core); Q stored = 16*true; combine /16 per seg.

#define NSITES 128
#define FEATD  64
#define BOND   32
#define OUTD   256
#define BT     16
#define SEGLEN 32
#define NSEG   (NSITES / SEGLEN)   // 4
#define NBT    (2048 / BT)         // 128

#define MS_RS  648                 // MS row stride (32 batches*... = 16*40+8 pad)
#define MS_BS  40                  // batch stride within row (32 B + 8 pad)

typedef __attribute__((ext_vector_type(4)))  float float4v;
typedef __attribute__((ext_vector_type(16))) float float16v;

__device__ __forceinline__ unsigned pk4_fp8(float a, float b, float c, float d) {
    int v = __builtin_amdgcn_cvt_pk_fp8_f32(a, b, 0, false);
    v = __builtin_amdgcn_cvt_pk_fp8_f32(c, d, v, true);
    return (unsigned)v;
}
__device__ __forceinline__ long mklong(int lo, int hi) {
    return ((long)(unsigned)lo) | (((long)hi) << 32);
}

// cores [n][d][f][r] fp32 -> core8 [n][c=d*32+r][f] fp8 (x16), LDS transpose.
__global__ __launch_bounds__(256)
void prep_cores8(const float* __restrict__ cores, unsigned char* __restrict__ core8) {
    __shared__ float tile[FEATD][BOND + 4];
    const int nd = blockIdx.x;            // n*32 + d
    const int t  = threadIdx.x;
    const float* src = cores + (size_t)nd * (FEATD * BOND);
    {
        int base = t * 8;
        int f = base >> 5, r0 = base & 31;
        float4 v0 = *(const float4*)(src + base);
        float4 v1 = *(const float4*)(src + base + 4);
        tile[f][r0 + 0] = v0.x; tile[f][r0 + 1] = v0.y;
        tile[f][r0 + 2] = v0.z; tile[f][r0 + 3] = v0.w;
        tile[f][r0 + 4] = v1.x; tile[f][r0 + 5] = v1.y;
        tile[f][r0 + 6] = v1.z; tile[f][r0 + 7] = v1.w;
    }
    __syncthreads();
    const int r = t >> 3, f0 = (t & 7) * 8;
    const float s = 16.0f;
    unsigned lo = pk4_fp8(tile[f0 + 0][r] * s, tile[f0 + 1][r] * s,
                          tile[f0 + 2][r] * s, tile[f0 + 3][r] * s);
    unsigned hi = pk4_fp8(tile[f0 + 4][r] * s, tile[f0 + 5][r] * s,
                          tile[f0 + 6][r] * s, tile[f0 + 7][r] * s);
    uint2 w; w.x = lo; w.y = hi;
    *(uint2*)(core8 + ((size_t)nd * BOND + r) * FEATD + f0) = w;
}

__global__ __launch_bounds__(512, 4)   // <=128 VGPR+AGPR, 2 blocks/CU
void mps_seg(const float* __restrict__ x, const unsigned char* __restrict__ core8,
             unsigned char* __restrict__ Pout) {
    __shared__ __align__(16) unsigned char MS[BOND * MS_RS];  // 20736 B, [r][b][d]
    __shared__ __align__(16) unsigned char XS[BT * 72];       //  1152 B

    const int t    = threadIdx.x;
    const int wave = t >> 6;          // 0..7
    const int lane = t & 63;
    const int cl   = lane & 15;
    const int q    = lane >> 4;
    const int l    = lane & 31;       // 32-row index for product
    const int h    = lane >> 5;       // 32x32 half
    const int b0   = blockIdx.x * BT;
    const int seg  = blockIdx.y;

    // Q = P^T = 16*I, packed fp8: lane(l,h) dword g byte i <-> Q[row 8g+4h+i][col l]
    int pq[2][4];
    {
        int g0 = l >> 3;
        int hm = ((l >> 2) & 1) == h;
#pragma unroll
        for (int bi = 0; bi < 2; ++bi)
#pragma unroll
            for (int g = 0; g < 4; ++g)
                pq[bi][g] = (g == g0 && hm) ? (0x58 << ((l & 3) * 8)) : 0;
    }
    const int paddr = (lane ^ 32) << 2;   // ds_bpermute addr for lane^32 swap

    const int xb = t >> 5, xf = (t & 31) * 2;
    {   // stage XS for site 0
        float2 x0 = *(const float2*)(x + ((size_t)(b0 + xb) * NSITES + seg * SEGLEN) * FEATD + xf);
        int v = __builtin_amdgcn_cvt_pk_fp8_f32(x0.x, x0.y, 0, false);
        *(unsigned short*)&XS[xb * 72 + xf] = (unsigned short)(v & 0xffff);
    }
    // A-fragment lane offset (site-invariant): tiles T = wave*8 + i
    const unsigned afoff = (unsigned)((wave * 128 + cl) * FEATD + q * 8);
    long af[16];
    {
        const unsigned char* p0 = core8 + (size_t)(seg * SEGLEN) * (1024 * FEATD) + afoff;
#pragma unroll
        for (int i = 0; i < 8; ++i) {
            af[i * 2 + 0] = *(const long*)(p0 + i * (16 * FEATD));
            af[i * 2 + 1] = *(const long*)(p0 + i * (16 * FEATD) + 32);
        }
    }

    for (int k = 0; k < SEGLEN; ++k) {
        const int n = seg * SEGLEN + k;
        __syncthreads();   // barrier A: XS(k) visible; MS(k-1) reads done; af(k) arrived

        // build: m^T[c,b], tiles T = wave*8+i, c = T*16 + 4q+g, b = cl
        long bx0 = *(const long*)&XS[cl * 72 + q * 8];
        long bx1 = *(const long*)&XS[cl * 72 + 32 + q * 8];
        float4v acc[8];
#pragma unroll
        for (int i = 0; i < 8; ++i) {
            float4v z = {0.f, 0.f, 0.f, 0.f};
            z = __builtin_amdgcn_mfma_f32_16x16x32_fp8_fp8(af[i * 2 + 0], bx0, z, 0, 0, 0);
            acc[i] = __builtin_amdgcn_mfma_f32_16x16x32_fp8_fp8(af[i * 2 + 1], bx1, z, 0, 0, 0);
        }
        // MS[r = 16p+4q+g][b = cl][d-pack w]: bytes u=0..3 <-> d = wave*4+u (tile 2u+p)
#pragma unroll
        for (int p = 0; p < 2; ++p)
#pragma unroll
            for (int g = 0; g < 4; ++g) {
                unsigned w = pk4_fp8(acc[p][g], acc[p + 2][g], acc[p + 4][g], acc[p + 6][g]);
                *(unsigned*)&MS[(16 * p + 4 * q + g) * MS_RS + cl * MS_BS + wave * 4] = w;
            }

        __syncthreads();   // barrier B: MS(k) visible

        // prefetch af(k+1) + x(k+1): latency hidden under product phase
        float2 xn;
        if (k + 1 < SEGLEN) {
            xn = *(const float2*)(x + ((size_t)(b0 + xb) * NSITES + n + 1) * FEATD + xf);
            const unsigned char* p1 = core8 + (size_t)(n + 1) * (1024 * FEATD) + afoff;
#pragma unroll
            for (int i = 0; i < 8; ++i) {
                af[i * 2 + 0] = *(const long*)(p1 + i * (16 * FEATD));
                af[i * 2 + 1] = *(const long*)(p1 + i * (16 * FEATD) + 32);
            }
        }

        // product: Q <- M^T * Q per batch (wave owns batches wave*2, wave*2+1)
#pragma unroll
        for (int bi = 0; bi < 2; ++bi) {
            const int bb = wave * 2 + bi;
            // A = M^T[row l][k=d]: instr0 k=8h+j, instr1 k=16+8h+j
            long a0 = *(const long*)&MS[l * MS_RS + bb * MS_BS + 8 * h];
            long a1 = *(const long*)&MS[l * MS_RS + bb * MS_BS + 16 + 8 * h];
            // B from Q regs: partner-dword swap (lane^32) + h-select
            int x0 = __builtin_amdgcn_ds_bpermute(paddr, pq[bi][0]);
            int x1 = __builtin_amdgcn_ds_bpermute(paddr, pq[bi][1]);
            int x2 = __builtin_amdgcn_ds_bpermute(paddr, pq[bi][2]);
            int x3 = __builtin_amdgcn_ds_bpermute(paddr, pq[bi][3]);
            long bf0 = h ? mklong(x1, pq[bi][1]) : mklong(pq[bi][0], x0);
            long bf1 = h ? mklong(x3, pq[bi][3]) : mklong(pq[bi][2], x2);
            float16v pc;
#pragma unroll
            for (int i = 0; i < 16; ++i) pc[i] = 0.f;
            pc = __builtin_amdgcn_mfma_f32_32x32x16_fp8_fp8(a0, bf0, pc, 0, 0, 0);
            pc = __builtin_amdgcn_mfma_f32_32x32x16_fp8_fp8(a1, bf1, pc, 0, 0, 0);
            // repack to fp8 (scale 1/16): dword g = rows 8g+4h+0..3 (regs 4g..4g+3)
#pragma unroll
            for (int g = 0; g < 4; ++g)
                pq[bi][g] = (int)pk4_fp8(pc[4 * g + 0] * 0.0625f, pc[4 * g + 1] * 0.0625f,
                                         pc[4 * g + 2] * 0.0625f, pc[4 * g + 3] * 0.0625f);
        }

        // stage XS(k+1): all XS(k) reads happened before barrier B
        if (k + 1 < SEGLEN) {
            int v = __builtin_amdgcn_cvt_pk_fp8_f32(xn.x, xn.y, 0, false);
            *(unsigned short*)&XS[xb * 72 + xf] = (unsigned short)(v & 0xffff);
        }
    }

    // dump Q (=P^T) -> Pout[seg][b][alpha=l][beta]: dword g at l*32 + 8g + 4h
#pragma unroll
    for (int bi = 0; bi < 2; ++bi) {
        const int bb = wave * 2 + bi;
        unsigned char* gp = Pout + (((size_t)seg * 2048 + b0 + bb) * 1024);
#pragma unroll
        for (int g = 0; g < 4; ++g)
            *(unsigned*)(gp + l * 32 + 8 * g + 4 * h) = (unsigned)pq[bi][g];
    }
}

// one wave per batch: res'[beta] = sum_alpha res[alpha] * fp8(P[alpha][beta]) / 16
__global__ __launch_bounds__(512)
void combine(const unsigned char* __restrict__ Pout, const float* __restrict__ startv,
             const float* __restrict__ endv, const float* __restrict__ fc_w,
             const float* __restrict__ fc_b, float* __restrict__ out) {
    const int t    = threadIdx.x;
    const int wave = t >> 6;
    const int lane = t & 63;
    const int r    = lane >> 1;   // beta, duplicated on lane pairs
    const int dh   = lane & 1;    // alpha half
    const int b    = blockIdx.x * 8 + wave;

    float res = startv[r];
    const unsigned char* base = Pout + (size_t)b * 1024 + dh * 512 + r;

    unsigned char by[16];
#pragma unroll
    for (int di = 0; di < 16; ++di) by[di] = base[di * 32];

    for (int s = 0; s < NSEG; ++s) {
        unsigned char by2[16];
        if (s + 1 < NSEG) {
            const unsigned char* nb = base + (size_t)(s + 1) * 2048 * 1024;
#pragma unroll
            for (int di = 0; di < 16; ++di) by2[di] = nb[di * 32];
        }
        float acc = 0.f;
#pragma unroll
        for (int di = 0; di < 16; ++di) {
            float rv = __shfl(res, dh * 32 + di * 2, 64);   // res[alpha], alpha=dh*16+di
            acc += rv * __builtin_amdgcn_cvt_f32_fp8((int)by[di], 0);
        }
        float tot = acc + __shfl_xor(acc, 1, 64);
        res = tot * 0.0625f;
        if (s + 1 < NSEG) {
#pragma unroll
            for (int di = 0; di < 16; ++di) by[di] = by2[di];
        }
    }

    float v = dh ? 0.f : res * endv[r];
#pragma unroll
    for (int off = 1; off < 64; off <<= 1) v += __shfl_xor(v, off, 64);

    const int j = lane * 4;
    float4 w4  = *(const float4*)(fc_w + j);
    float4 bb4 = *(const float4*)(fc_b + j);
    float4 o;
    o.x = v * w4.x + bb4.x;
    o.y = v * w4.y + bb4.y;
    o.z = v * w4.z + bb4.z;
    o.w = v * w4.w + bb4.w;
    *(float4*)(out + (size_t)b * OUTD + j) = o;
}

extern "C" void kernel_launch(void* const* d_in, const int* in_sizes, int n_in,
                              void* d_out, int out_size, void* d_ws, size_t ws_size,
                              hipStream_t stream) {
    const float* x      = (const float*)d_in[0];
    const float* cores  = (const float*)d_in[1];
    const float* startv = (const float*)d_in[2];
    const float* endv   = (const float*)d_in[3];
    const float* fc_w   = (const float*)d_in[4];
    const float* fc_b   = (const float*)d_in[5];
    float* out = (float*)d_out;

    unsigned char* core8 = (unsigned char*)d_ws;                       // 8.4 MB
    unsigned char* Pout  = core8 + (size_t)NSITES * 1024 * FEATD;      // 8.4 MB

    prep_cores8<<<NSITES * BOND, 256, 0, stream>>>(cores, core8);
    mps_seg<<<dim3(NBT, NSEG), 512, 0, stream>>>(x, core8, Pout);
    combine<<<2048 / 8, 512, 0, stream>>>(Pout, startv, endv, fc_w, fc_b, out);
}

// Round 6
// 245.404 us; speedup vs baseline: 1.0948x; 1.0309x over previous
//
#include <hip/hip_runtime.h>

// MPS encoder, segmented chain, single-barrier software pipeline.
// Phase k: build M(k) into MS[k&1]  ||  product applies M(k-1) from MS[(k-1)&1].
// One __syncthreads per phase; build MFMA throughput hides the product's
// dependent chain (ds_read -> bpermute -> 2x mfma_32x32x16 -> repack).
// BT=16, SEGLEN=32, NSEG=4, 512-thr blocks, grid 128x4 = 2 blocks/CU.
// Scaling: core8 = fp8(16*core); Q stored = 16*true; combine /16 per seg.

#define NSITES 128
#define FEATD  64
#define BOND   32
#define OUTD   256
#define BT     16
#define SEGLEN 32
#define NSEG   (NSITES / SEGLEN)   // 4
#define NBT    (2048 / BT)         // 128

#define MS_RS  648                 // MS row stride bytes
#define MS_BS  40                  // batch stride within row (32 B + 8 pad)

typedef __attribute__((ext_vector_type(4)))  float float4v;
typedef __attribute__((ext_vector_type(16))) float float16v;

__device__ __forceinline__ unsigned pk4_fp8(float a, float b, float c, float d) {
    int v = __builtin_amdgcn_cvt_pk_fp8_f32(a, b, 0, false);
    v = __builtin_amdgcn_cvt_pk_fp8_f32(c, d, v, true);
    return (unsigned)v;
}
__device__ __forceinline__ long mklong(int lo, int hi) {
    return ((long)(unsigned)lo) | (((long)hi) << 32);
}

// cores [n][d][f][r] fp32 -> core8 [n][c=d*32+r][f] fp8 (x16), LDS transpose.
__global__ __launch_bounds__(256)
void prep_cores8(const float* __restrict__ cores, unsigned char* __restrict__ core8) {
    __shared__ float tile[FEATD][BOND + 4];
    const int nd = blockIdx.x;            // n*32 + d
    const int t  = threadIdx.x;
    const float* src = cores + (size_t)nd * (FEATD * BOND);
    {
        int base = t * 8;
        int f = base >> 5, r0 = base & 31;
        float4 v0 = *(const float4*)(src + base);
        float4 v1 = *(const float4*)(src + base + 4);
        tile[f][r0 + 0] = v0.x; tile[f][r0 + 1] = v0.y;
        tile[f][r0 + 2] = v0.z; tile[f][r0 + 3] = v0.w;
        tile[f][r0 + 4] = v1.x; tile[f][r0 + 5] = v1.y;
        tile[f][r0 + 6] = v1.z; tile[f][r0 + 7] = v1.w;
    }
    __syncthreads();
    const int r = t >> 3, f0 = (t & 7) * 8;
    const float s = 16.0f;
    unsigned lo = pk4_fp8(tile[f0 + 0][r] * s, tile[f0 + 1][r] * s,
                          tile[f0 + 2][r] * s, tile[f0 + 3][r] * s);
    unsigned hi = pk4_fp8(tile[f0 + 4][r] * s, tile[f0 + 5][r] * s,
                          tile[f0 + 6][r] * s, tile[f0 + 7][r] * s);
    uint2 w; w.x = lo; w.y = hi;
    *(uint2*)(core8 + ((size_t)nd * BOND + r) * FEATD + f0) = w;
}

__device__ __forceinline__ void product_step(const unsigned char* __restrict__ MSb,
                                             int pq[2][4], int wave, int l, int h,
                                             int paddr) {
#pragma unroll
    for (int bi = 0; bi < 2; ++bi) {
        const int bb = wave * 2 + bi;
        long a0 = *(const long*)&MSb[l * MS_RS + bb * MS_BS + 8 * h];
        long a1 = *(const long*)&MSb[l * MS_RS + bb * MS_BS + 16 + 8 * h];
        int x0 = __builtin_amdgcn_ds_bpermute(paddr, pq[bi][0]);
        int x1 = __builtin_amdgcn_ds_bpermute(paddr, pq[bi][1]);
        int x2 = __builtin_amdgcn_ds_bpermute(paddr, pq[bi][2]);
        int x3 = __builtin_amdgcn_ds_bpermute(paddr, pq[bi][3]);
        long bf0 = h ? mklong(x1, pq[bi][1]) : mklong(pq[bi][0], x0);
        long bf1 = h ? mklong(x3, pq[bi][3]) : mklong(pq[bi][2], x2);
        float16v pc;
#pragma unroll
        for (int i = 0; i < 16; ++i) pc[i] = 0.f;
        pc = __builtin_amdgcn_mfma_f32_32x32x16_fp8_fp8(a0, bf0, pc, 0, 0, 0);
        pc = __builtin_amdgcn_mfma_f32_32x32x16_fp8_fp8(a1, bf1, pc, 0, 0, 0);
#pragma unroll
        for (int g = 0; g < 4; ++g)
            pq[bi][g] = (int)pk4_fp8(pc[4 * g + 0] * 0.0625f, pc[4 * g + 1] * 0.0625f,
                                     pc[4 * g + 2] * 0.0625f, pc[4 * g + 3] * 0.0625f);
    }
}

__global__ __launch_bounds__(512, 4)   // 2 blocks/CU (LDS-bound at 44 KB)
void mps_seg(const float* __restrict__ x, const unsigned char* __restrict__ core8,
             unsigned char* __restrict__ Pout) {
    __shared__ __align__(16) unsigned char MS[2][BOND * MS_RS];  // 2 x 20736 B
    __shared__ __align__(16) unsigned char XS[2][BT * 72];       // 2 x  1152 B

    const int t    = threadIdx.x;
    const int wave = t >> 6;          // 0..7
    const int lane = t & 63;
    const int cl   = lane & 15;
    const int q    = lane >> 4;
    const int l    = lane & 31;
    const int h    = lane >> 5;
    const int b0   = blockIdx.x * BT;
    const int seg  = blockIdx.y;
    const int n0   = seg * SEGLEN;

    // Q = P^T = 16*I, packed fp8 (fp8(16) = 0x58)
    int pq[2][4];
    {
        int g0 = l >> 3;
        int hm = ((l >> 2) & 1) == h;
#pragma unroll
        for (int bi = 0; bi < 2; ++bi)
#pragma unroll
            for (int g = 0; g < 4; ++g)
                pq[bi][g] = (g == g0 && hm) ? (0x58 << ((l & 3) * 8)) : 0;
    }
    const int paddr = (lane ^ 32) << 2;

    const int xb = t >> 5, xf = (t & 31) * 2;
    const unsigned afoff = (unsigned)((wave * 128 + cl) * FEATD + q * 8);

    // preheader: XS[0] <- x(site 0); xr <- x(site 1); af <- site 0
    {
        float2 x0 = *(const float2*)(x + ((size_t)(b0 + xb) * NSITES + n0) * FEATD + xf);
        int v = __builtin_amdgcn_cvt_pk_fp8_f32(x0.x, x0.y, 0, false);
        *(unsigned short*)&XS[0][xb * 72 + xf] = (unsigned short)(v & 0xffff);
    }
    float2 xr = *(const float2*)(x + ((size_t)(b0 + xb) * NSITES + n0 + 1) * FEATD + xf);
    long af[16];
    {
        const unsigned char* p0 = core8 + (size_t)n0 * (1024 * FEATD) + afoff;
#pragma unroll
        for (int i = 0; i < 8; ++i) {
            af[i * 2 + 0] = *(const long*)(p0 + i * (16 * FEATD));
            af[i * 2 + 1] = *(const long*)(p0 + i * (16 * FEATD) + 32);
        }
    }
    __syncthreads();

    for (int k = 0; k < SEGLEN; ++k) {
        const int par = k & 1;
        const int n = n0 + k;

        // stage XS[par^1] <- xr = x(k+1)  (its reads finished in phase k-1)
        if (k + 1 < SEGLEN) {
            int v = __builtin_amdgcn_cvt_pk_fp8_f32(xr.x, xr.y, 0, false);
            *(unsigned short*)&XS[par ^ 1][xb * 72 + xf] = (unsigned short)(v & 0xffff);
        }
        // issue load x(k+2); arrives during phase k+1
        if (k + 2 < SEGLEN)
            xr = *(const float2*)(x + ((size_t)(b0 + xb) * NSITES + n + 2) * FEATD + xf);

        // build site k from XS[par] into MS[par] (two parity groups, low reg)
        long bx0 = *(const long*)&XS[par][cl * 72 + q * 8];
        long bx1 = *(const long*)&XS[par][cl * 72 + 32 + q * 8];
#pragma unroll
        for (int p = 0; p < 2; ++p) {
            float4v acc[4];
#pragma unroll
            for (int u = 0; u < 4; ++u) {
                float4v z = {0.f, 0.f, 0.f, 0.f};
                z = __builtin_amdgcn_mfma_f32_16x16x32_fp8_fp8(af[(2 * u + p) * 2], bx0, z, 0, 0, 0);
                acc[u] = __builtin_amdgcn_mfma_f32_16x16x32_fp8_fp8(af[(2 * u + p) * 2 + 1], bx1, z, 0, 0, 0);
            }
#pragma unroll
            for (int g = 0; g < 4; ++g) {
                unsigned w = pk4_fp8(acc[0][g], acc[1][g], acc[2][g], acc[3][g]);
                *(unsigned*)&MS[par][(16 * p + 4 * q + g) * MS_RS + cl * MS_BS + wave * 4] = w;
            }
        }

        // prefetch af(k+1): covered by product + barrier + next phase start
        if (k + 1 < SEGLEN) {
            const unsigned char* p1 = core8 + (size_t)(n + 1) * (1024 * FEATD) + afoff;
#pragma unroll
            for (int i = 0; i < 8; ++i) {
                af[i * 2 + 0] = *(const long*)(p1 + i * (16 * FEATD));
                af[i * 2 + 1] = *(const long*)(p1 + i * (16 * FEATD) + 32);
            }
        }

        // product: apply M(k-1) from MS[par^1] (overlaps build's MFMA stream)
        if (k > 0) product_step(MS[par ^ 1], pq, wave, l, h, paddr);

        __syncthreads();
    }
    // epilogue: apply M(SEGLEN-1)
    product_step(MS[(SEGLEN - 1) & 1], pq, wave, l, h, paddr);

    // dump Q (=P^T) -> Pout[seg][b][alpha=l][beta]: dword g at l*32 + 8g + 4h
#pragma unroll
    for (int bi = 0; bi < 2; ++bi) {
        const int bb = wave * 2 + bi;
        unsigned char* gp = Pout + (((size_t)seg * 2048 + b0 + bb) * 1024);
#pragma unroll
        for (int g = 0; g < 4; ++g)
            *(unsigned*)(gp + l * 32 + 8 * g + 4 * h) = (unsigned)pq[bi][g];
    }
}

// combine: 16 batches/block, coalesced LDS staging, seg-sequential matvec.
__global__ __launch_bounds__(256)
void combine(const unsigned char* __restrict__ Pout, const float* __restrict__ startv,
             const float* __restrict__ endv, const float* __restrict__ fc_w,
             const float* __restrict__ fc_b, float* __restrict__ out) {
    __shared__ __align__(16) unsigned char st[16 * 1024];
    __shared__ float resA[16][34], resB[16][34];
    __shared__ float val_lds[16];
    const int t  = threadIdx.x;
    const int b0 = blockIdx.x * 16;
    const int bt = t >> 4;        // batch 0..15
    const int c  = t & 15;        // beta pair index

    for (int e = t; e < 512; e += 256) resA[e >> 5][e & 31] = startv[e & 31];

    for (int s = 0; s < NSEG; ++s) {
        {   // stage 16 KB coalesced
            const uint4* g = (const uint4*)(Pout + ((size_t)s * 2048 + b0) * 1024);
#pragma unroll
            for (int it = 0; it < 4; ++it)
                *(uint4*)&st[(it * 256 + t) * 16] = g[it * 256 + t];
        }
        __syncthreads();
        const float* rin = (s & 1) ? &resB[bt][0] : &resA[bt][0];
        float* rout      = (s & 1) ? &resA[bt][0] : &resB[bt][0];
        float a0 = 0.f, a1 = 0.f;
#pragma unroll
        for (int alpha = 0; alpha < BOND; ++alpha) {
            float rv = rin[alpha];
            unsigned short pp = *(const unsigned short*)&st[bt * 1024 + alpha * 32 + 2 * c];
            a0 += rv * __builtin_amdgcn_cvt_f32_fp8((int)(pp & 0xff), 0);
            a1 += rv * __builtin_amdgcn_cvt_f32_fp8((int)(pp >> 8), 0);
        }
        rout[2 * c]     = a0 * 0.0625f;
        rout[2 * c + 1] = a1 * 0.0625f;
        __syncthreads();
    }

    // val[bt] = res . end   (NSEG even -> result in resA)
    float pv = resA[bt][2 * c] * endv[2 * c] + resA[bt][2 * c + 1] * endv[2 * c + 1];
#pragma unroll
    for (int off = 1; off < 16; off <<= 1) pv += __shfl_xor(pv, off, 64);
    if (c == 0) val_lds[bt] = pv;
    __syncthreads();

    const float v = val_lds[bt];
#pragma unroll
    for (int i = 0; i < 4; ++i) {
        int j = c * 4 + i * 64;
        float4 w4  = *(const float4*)(fc_w + j);
        float4 bb4 = *(const float4*)(fc_b + j);
        float4 o;
        o.x = v * w4.x + bb4.x;
        o.y = v * w4.y + bb4.y;
        o.z = v * w4.z + bb4.z;
        o.w = v * w4.w + bb4.w;
        *(float4*)(out + (size_t)(b0 + bt) * OUTD + j) = o;
    }
}

extern "C" void kernel_launch(void* const* d_in, const int* in_sizes, int n_in,
                              void* d_out, int out_size, void* d_ws, size_t ws_size,
                              hipStream_t stream) {
    const float* x      = (const float*)d_in[0];
    const float* cores  = (const float*)d_in[1];
    const float* startv = (const float*)d_in[2];
    const float* endv   = (const float*)d_in[3];
    const float* fc_w   = (const float*)d_in[4];
    const float* fc_b   = (const float*)d_in[5];
    float* out = (float*)d_out;

    unsigned char* core8 = (unsigned char*)d_ws;                       // 8.4 MB
    unsigned char* Pout  = core8 + (size_t)NSITES * 1024 * FEATD;      // 8.4 MB

    prep_cores8<<<NSITES * BOND, 256, 0, stream>>>(cores, core8);
    mps_seg<<<dim3(NBT, NSEG), 512, 0, stream>>>(x, core8, Pout);
    combine<<<2048 / 16, 256, 0, stream>>>(Pout, startv, endv, fc_w, fc_b, out);
}